// Round 8
// baseline (27.128 us; speedup 1.0000x reference)
//
#include <hip/hip_runtime.h>

#define NB   384
#define ND   256
#define EPSF 1e-6f

// ws layout (floats):
#define WF_OFF   0                        // wf[4] = tw_t / count_t
#define PART_OFF 16                       // partial[384]
#define D_OFF    1024                     // D[384][384]
#define ET_OFF   (D_OFF + NB * NB)        // ET[256][384] = emb^T - eps

// ---------------------------------------------------------------------------
// K1: transpose emb -> ET[d][j] = e[j][d] - eps; block 0 also computes
// wf[t] = tw_t / count_t from the analytic rank-histogram count.
// ---------------------------------------------------------------------------
__global__ __launch_bounds__(256) void prep_kernel(
    const float* __restrict__ emb,
    const float* __restrict__ tw,
    const int*   __restrict__ rank,
    float* __restrict__ ws)
{
    __shared__ float    t[32][33];
    __shared__ unsigned hist[20];

    const int tid = threadIdx.x;
    const int dt  = blockIdx.x & 7;
    const int jt  = blockIdx.x >> 3;
    const int c   = tid & 31;
    const int r8  = tid >> 5;

    #pragma unroll
    for (int p = 0; p < 4; ++p) {
        const int j = jt * 32 + r8 + p * 8;
        const int d = dt * 32 + c;
        t[r8 + p * 8][c] = emb[(size_t)j * ND + d];
    }
    __syncthreads();
    float* ET = ws + ET_OFF;
    #pragma unroll
    for (int p = 0; p < 4; ++p) {
        const int d = dt * 32 + r8 + p * 8;
        const int j = jt * 32 + c;
        ET[(size_t)d * NB + j] = t[c][r8 + p * 8] - EPSF;
    }

    if (blockIdx.x == 0) {
        if (tid < 20) hist[tid] = 0u;
        __syncthreads();
        for (int e = tid; e < NB * 4; e += 256)
            atomicAdd(&hist[(e & 3) * 5 + rank[e]], 1u);
        __syncthreads();
        if (tid < 4) {
            double cnt = 0.0;
            unsigned below = 0;
            #pragma unroll
            for (int v = 0; v < 5; ++v) {
                unsigned hv = hist[tid * 5 + v];
                unsigned above = (unsigned)NB - below - hv;
                cnt += (double)hv * (double)below * (double)above;
                below += hv;
            }
            ws[WF_OFF + tid] = (cnt > 0.0) ? (float)((double)tw[tid] / cnt) : 0.f;
        }
    }
}

// ---------------------------------------------------------------------------
// K2: D[i][j]. Block = 2 i-rows x 192 j-cols -> grid (192,2) = 384 blocks,
// 192 thr (3 waves). ET column loads lane-coalesced, 8-deep batches (x2
// unroll = 16 in flight); e_i rows wave-uniform -> scalar path.
// ---------------------------------------------------------------------------
__global__ __launch_bounds__(192) void dist_kernel(
    const float* __restrict__ emb,
    const float* __restrict__ et,
    float* __restrict__ D)
{
    const int j  = blockIdx.y * 192 + threadIdx.x;
    const int i0 = blockIdx.x * 2;
    const float* e0 = emb + (size_t)i0 * ND;
    const float* e1 = e0 + ND;
    const float* etc = et + j;

    float a0 = 0.f, a1 = 0.f;
    #pragma unroll 2
    for (int d0 = 0; d0 < ND; d0 += 8) {
        float l[8];
        #pragma unroll
        for (int u = 0; u < 8; ++u)
            l[u] = etc[(size_t)(d0 + u) * NB];
        #pragma unroll
        for (int u = 0; u < 8; ++u) {
            const float t0 = e0[d0 + u] - l[u];
            const float t1 = e1[d0 + u] - l[u];
            a0 = fmaf(t0, t0, a0);
            a1 = fmaf(t1, t1, a1);
        }
    }
    D[(size_t)i0 * NB + j]       = sqrtf(a0);
    D[(size_t)(i0 + 1) * NB + j] = sqrtf(a1);
}

// ---------------------------------------------------------------------------
// K3: one block per row i (no dist phase, no launch-bounds VGPR cap).
//  - load D row, pack ranks from global
//  - hybrid bitonic sort of (quantized-key | idx): 39 shfl + 6 LDS stages
//  - ballot cumulative-rank masks, dual binary search, weighted counts:
//    j-role: + thr_p * sum_t wf_t * #{q<P: r^t_q < r^t_p}     [r^t_p < r^t_i]
//    k-role: - d_p  * sum_t wf_t * #{q>=Q: r^t_p < r^t_q < r^t_i}
// ---------------------------------------------------------------------------
__global__ __launch_bounds__(512) void loss_kernel(
    const float* __restrict__ D,
    const int*   __restrict__ rank,
    const float* __restrict__ wf,
    float* __restrict__ partial)
{
    __shared__ float    dv[512];
    __shared__ unsigned rpl[512];
    __shared__ unsigned s32[512];
    __shared__ float    ks[512];
    __shared__ unsigned long long cm[8][16];
    __shared__ unsigned cumtab[9][16];
    __shared__ float    red[8];

    const int p  = threadIdx.x;
    const int bi = blockIdx.x;

    unsigned sk;
    if (p < NB) {
        const float key = D[(size_t)bi * NB + p];
        const int4 r4 = *reinterpret_cast<const int4*>(rank + p * 4);
        dv[p]  = key;
        rpl[p] = (unsigned)r4.x | ((unsigned)r4.y << 8) |
                 ((unsigned)r4.z << 16) | ((unsigned)r4.w << 24);
        sk = (__float_as_uint(key) & ~0x1FFu) | (unsigned)p;   // key|idx (d>0)
    } else {
        dv[p]  = __int_as_float(0x7F800000);
        rpl[p] = 0xFFFFFFFFu;
        sk = 0xFFFFFFFFu;                  // pads sort last
    }

    // hybrid bitonic sort (ascending): strides <64 via shfl_xor, >=64 via LDS
    #pragma unroll
    for (int size = 2; size <= 512; size <<= 1) {
        #pragma unroll
        for (int stride = size >> 1; stride > 0; stride >>= 1) {
            unsigned other;
            if (stride >= 64) {
                __syncthreads();
                s32[p] = sk;
                __syncthreads();
                other = s32[p ^ stride];
            } else {
                other = (unsigned)__shfl_xor((int)sk, stride, 64);
            }
            const bool keepMin = ((p & stride) == 0) == ((p & size) == 0);
            sk = ((sk < other) == keepMin) ? sk : other;
        }
    }

    const int idx = (int)(sk & 0x1FFu);
    __syncthreads();
    const float    key = dv[idx];          // exact key, sorted order
    const unsigned rsv = rpl[idx];
    ks[p] = key;

    const int wv = p >> 6;
    #pragma unroll
    for (int t = 0; t < 4; ++t) {
        const unsigned rt = (rsv >> (8 * t)) & 0xFFu;
        #pragma unroll
        for (int w = 0; w < 4; ++w) {
            const unsigned long long m = __ballot(rt <= (unsigned)w);
            if ((p & 63) == 0) cm[wv][t * 4 + w] = m;
        }
    }
    __syncthreads();
    if (p < 16) {
        unsigned c = 0;
        #pragma unroll
        for (int w2 = 0; w2 < 8; ++w2) {
            cumtab[w2][p] = c;
            c += (unsigned)__popcll(cm[w2][p]);
        }
        cumtab[8][p] = c;
    }
    __syncthreads();

    float contrib = 0.f;
    if (p < NB) {
        const float thr = key + 1.0f;

        int P = 0, Q = 0;
        #pragma unroll
        for (int s = 256; s > 0; s >>= 1) {
            if (ks[P + s - 1] < thr)         P += s;
            if (ks[Q + s - 1] + 1.0f <= key) Q += s;
        }

        const int Pwv = P >> 6, Qwv = Q >> 6;
        const unsigned long long Pmask = (1ull << (P & 63)) - 1ull;
        const unsigned long long Qmask = (1ull << (Q & 63)) - 1ull;
        const int4 ri4 = *reinterpret_cast<const int4*>(rank + bi * 4);
        const unsigned rip = (unsigned)ri4.x | ((unsigned)ri4.y << 8) |
                             ((unsigned)ri4.z << 16) | ((unsigned)ri4.w << 24);

        float jacc = 0.f, kacc = 0.f;
        #pragma unroll
        for (int t = 0; t < 4; ++t) {
            const int ri = (int)((rip >> (8 * t)) & 0xFFu);
            const int ro = (int)((rsv >> (8 * t)) & 0xFFu);
            const float wt = wf[t];
            if (ro > 0 && ro < ri) {                       // j-role
                const int w = t * 4 + (ro - 1);
                const unsigned N = cumtab[Pwv][w] +
                                   (unsigned)__popcll(cm[Pwv][w] & Pmask);
                jacc += wt * (float)N;
            }
            if (ro + 1 < ri) {                             // k-role
                const int wh = t * 4 + (ri - 1);
                const int wl = t * 4 + ro;
                const unsigned cQh = cumtab[Qwv][wh] +
                                     (unsigned)__popcll(cm[Qwv][wh] & Qmask);
                const unsigned cQl = cumtab[Qwv][wl] +
                                     (unsigned)__popcll(cm[Qwv][wl] & Qmask);
                const unsigned C = (cumtab[8][wh] - cQh) - (cumtab[8][wl] - cQl);
                kacc += wt * (float)C;
            }
        }
        contrib = jacc * thr - kacc * key;
    }

    #pragma unroll
    for (int off = 32; off > 0; off >>= 1)
        contrib += __shfl_down(contrib, off);
    if ((p & 63) == 0) red[p >> 6] = contrib;
    __syncthreads();
    if (p == 0) {
        float s = 0.f;
        #pragma unroll
        for (int q = 0; q < 8; ++q) s += red[q];
        partial[bi] = s;
    }
}

// ---------------------------------------------------------------------------
// K4: reduce 384 partials -> out[0]
// ---------------------------------------------------------------------------
__global__ __launch_bounds__(256) void reduce_kernel(
    const float* __restrict__ partial, float* __restrict__ out)
{
    __shared__ float r[4];
    const int tid = threadIdx.x;
    float t = 0.f;
    for (int p = tid; p < NB; p += 256) t += partial[p];
    #pragma unroll
    for (int off = 32; off > 0; off >>= 1)
        t += __shfl_down(t, off);
    if ((tid & 63) == 0) r[tid >> 6] = t;
    __syncthreads();
    if (tid == 0) out[0] = r[0] + r[1] + r[2] + r[3];
}

extern "C" void kernel_launch(void* const* d_in, const int* in_sizes, int n_in,
                              void* d_out, int out_size, void* d_ws, size_t ws_size,
                              hipStream_t stream)
{
    (void)in_sizes; (void)n_in; (void)out_size; (void)ws_size;
    const float* emb  = (const float*)d_in[0];
    const float* tw   = (const float*)d_in[1];
    const int*   rank = (const int*)d_in[2];
    float* ws  = (float*)d_ws;
    float* out = (float*)d_out;

    prep_kernel<<<96, 256, 0, stream>>>(emb, tw, rank, ws);
    dist_kernel<<<dim3(192, 2), 192, 0, stream>>>(emb, ws + ET_OFF, ws + D_OFF);
    loss_kernel<<<NB, 512, 0, stream>>>(ws + D_OFF, rank, ws + WF_OFF,
                                        ws + PART_OFF);
    reduce_kernel<<<1, 256, 0, stream>>>(ws + PART_OFF, out);
}

// Round 9
// 24.192 us; speedup vs baseline: 1.1214x; 1.1214x over previous
//
#include <hip/hip_runtime.h>

#define NB   384
#define ND   256
#define EPSF 1e-6f
#define NBIN 512

// ws layout (floats):
#define WF_OFF   0                        // wf[4] = tw_t / count_t
#define PART_OFF 16                       // partial[384]
#define ET_OFF   1024                     // ET[256][384] = emb^T - eps

// ---------------------------------------------------------------------------
// K1: transpose emb -> ET[d][j] = e[j][d] - eps; block 0 also computes
// wf[t] = tw_t / count_t from the analytic rank-histogram count.
// ---------------------------------------------------------------------------
__global__ __launch_bounds__(256) void prep_kernel(
    const float* __restrict__ emb,
    const float* __restrict__ tw,
    const int*   __restrict__ rank,
    float* __restrict__ ws)
{
    __shared__ float    t[32][33];
    __shared__ unsigned hist[20];

    const int tid = threadIdx.x;
    const int dt  = blockIdx.x & 7;
    const int jt  = blockIdx.x >> 3;
    const int c   = tid & 31;
    const int r8  = tid >> 5;

    #pragma unroll
    for (int p = 0; p < 4; ++p) {
        const int j = jt * 32 + r8 + p * 8;
        const int d = dt * 32 + c;
        t[r8 + p * 8][c] = emb[(size_t)j * ND + d];
    }
    __syncthreads();
    float* ET = ws + ET_OFF;
    #pragma unroll
    for (int p = 0; p < 4; ++p) {
        const int d = dt * 32 + r8 + p * 8;
        const int j = jt * 32 + c;
        ET[(size_t)d * NB + j] = t[c][r8 + p * 8] - EPSF;
    }

    if (blockIdx.x == 0) {
        if (tid < 20) hist[tid] = 0u;
        __syncthreads();
        for (int e = tid; e < NB * 4; e += 256)
            atomicAdd(&hist[(e & 3) * 5 + rank[e]], 1u);
        __syncthreads();
        if (tid < 4) {
            double cnt = 0.0;
            unsigned below = 0;
            #pragma unroll
            for (int v = 0; v < 5; ++v) {
                unsigned hv = hist[tid * 5 + v];
                unsigned above = (unsigned)NB - below - hv;
                cnt += (double)hv * (double)below * (double)above;
                below += hv;
            }
            ws[WF_OFF + tid] = (cnt > 0.0) ? (float)((double)tw[tid] / cnt) : 0.f;
        }
    }
}

// ---------------------------------------------------------------------------
// K2 (fused, sort-free): one block per row i.
//  P1: d_p from ET (16-deep batched coalesced loads, e_i broadcast from LDS)
//  P2: row min/max -> integer scale S = bins per 1.0 distance
//      bin(d+1) == bin(d)+S exactly  =>  pair predicate  q_k < q_j + S
//  P3: 512-bin histogram -> exclusive prefix (shfl scan) -> counting scatter
//      of rank packs into d-grouped order (replaces the bitonic sort)
//  P4: ballot cumulative-rank masks over scattered order (as before)
//  P5: per element p (original):
//      j-role: +thr_p * sum_t wf_t * #{pos <  offs[q_p+S]: r^t < r^t_p}  [r^t_p < r^t_i]
//      k-role: -d_p  * sum_t wf_t * #{pos >= offs[q_p-S+1]: r^t_p < r^t < r^t_i}
//      Both sides index the SAME bin-boundary cuts -> pair sets identical.
// ---------------------------------------------------------------------------
__global__ __launch_bounds__(512) void loss_kernel(
    const float* __restrict__ emb,
    const float* __restrict__ et,
    const int*   __restrict__ rank,
    const float* __restrict__ wf,
    float* __restrict__ partial)
{
    __shared__ float    eil[ND];
    __shared__ unsigned hist[NBIN];
    __shared__ unsigned offs[NBIN + 1];
    __shared__ unsigned curs[NBIN];
    __shared__ unsigned srk[512];
    __shared__ unsigned long long cm[8][16];
    __shared__ unsigned cumtab[9][16];
    __shared__ unsigned wtot[8];
    __shared__ float    mmx[16];
    __shared__ float    sprm[2];
    __shared__ float    wfl[4];
    __shared__ float    red[8];

    const int p  = threadIdx.x;
    const int bi = blockIdx.x;
    const int wv = p >> 6;

    if (p < ND) eil[p] = emb[(size_t)bi * ND + p];
    if (p < 4)  wfl[p] = wf[p];
    hist[p] = 0u;
    if (p >= NB) srk[p] = 0xFFFFFFFFu;   // pads: rank bytes 0xFF (never counted)
    __syncthreads();

    // P1: distance
    float d = 0.f;
    if (p < NB) {
        float acc = 0.f;
        for (int d0 = 0; d0 < ND; d0 += 16) {
            float l[16];
            #pragma unroll
            for (int u = 0; u < 16; ++u)
                l[u] = et[(size_t)(d0 + u) * NB + p];
            #pragma unroll
            for (int u = 0; u < 16; ++u) {
                const float t = eil[d0 + u] - l[u];
                acc = fmaf(t, t, acc);
            }
        }
        d = sqrtf(acc);
    }

    // P2: min/max -> integer scale
    float dl = (p < NB) ? d : 3.0e38f;
    float dh = (p < NB) ? d : -3.0e38f;
    #pragma unroll
    for (int off = 32; off > 0; off >>= 1) {
        dl = fminf(dl, __shfl_xor(dl, off, 64));
        dh = fmaxf(dh, __shfl_xor(dh, off, 64));
    }
    if ((p & 63) == 0) { mmx[wv] = dl; mmx[8 + wv] = dh; }
    __syncthreads();
    if (p == 0) {
        float mn = mmx[0], mx = mmx[8];
        #pragma unroll
        for (int w = 1; w < 8; ++w) {
            mn = fminf(mn, mmx[w]);
            mx = fmaxf(mx, mmx[8 + w]);
        }
        int S = (int)(511.0f / (mx - mn + 1.0f));
        if (S < 1) S = 1;
        sprm[0] = mn;
        sprm[1] = (float)S;
    }
    __syncthreads();
    const float dmin   = sprm[0];
    const float scaleF = sprm[1];
    const int   S      = (int)scaleF;

    // P3a: histogram
    int q = 0;
    unsigned rpk = 0xFFFFFFFFu;
    if (p < NB) {
        q = (int)((d - dmin) * scaleF);
        if (q > NBIN - 1) q = NBIN - 1;
        atomicAdd(&hist[q], 1u);
        const int4 r4 = *reinterpret_cast<const int4*>(rank + p * 4);
        rpk = (unsigned)r4.x | ((unsigned)r4.y << 8) |
              ((unsigned)r4.z << 16) | ((unsigned)r4.w << 24);
    }
    __syncthreads();

    // P3b: exclusive prefix over 512 bins (wave shfl scan + cross-wave)
    const unsigned h = hist[p];
    unsigned inc = h;
    #pragma unroll
    for (int s = 1; s < 64; s <<= 1) {
        const unsigned o = __shfl_up(inc, s, 64);
        if ((p & 63) >= s) inc += o;
    }
    if ((p & 63) == 63) wtot[wv] = inc;
    __syncthreads();
    unsigned woff = 0;
    for (int w = 0; w < wv; ++w) woff += wtot[w];
    const unsigned excl = woff + inc - h;
    offs[p] = excl;
    curs[p] = excl;
    if (p == NBIN - 1) offs[NBIN] = excl + h;   // == NB
    __syncthreads();

    // P3c: counting scatter of rank packs into d-grouped order
    if (p < NB) {
        const unsigned pos = atomicAdd(&curs[q], 1u);
        srk[pos] = rpk;
    }
    __syncthreads();

    // P4: ballot cumulative-rank masks over scattered order
    const unsigned rsv = srk[p];
    #pragma unroll
    for (int t = 0; t < 4; ++t) {
        const unsigned rt = (rsv >> (8 * t)) & 0xFFu;
        #pragma unroll
        for (int w = 0; w < 4; ++w) {
            const unsigned long long m = __ballot(rt <= (unsigned)w);
            if ((p & 63) == 0) cm[wv][t * 4 + w] = m;
        }
    }
    __syncthreads();
    if (p < 16) {
        unsigned c = 0;
        #pragma unroll
        for (int w2 = 0; w2 < 8; ++w2) {
            cumtab[w2][p] = c;
            c += (unsigned)__popcll(cm[w2][p]);
        }
        cumtab[8][p] = c;
    }
    __syncthreads();

    // P5: per-element contribution (uses OWN exact d; cuts at bin boundaries)
    float contrib = 0.f;
    if (p < NB) {
        const float thr = d + 1.0f;
        const int jidx = (q + S > NBIN) ? NBIN : (q + S);
        const int kidx = (q - S + 1 < 0) ? 0 : (q - S + 1);
        const unsigned P = offs[jidx];     // #partners k (as j):  pos <  P
        const unsigned L = offs[kidx];     // partners j (as k):   pos >= L
        const int Pwv = (int)(P >> 6), Lwv = (int)(L >> 6);
        const unsigned long long Pmask = (1ull << (P & 63)) - 1ull;
        const unsigned long long Lmask = (1ull << (L & 63)) - 1ull;

        const int4 ri4 = *reinterpret_cast<const int4*>(rank + bi * 4);
        const unsigned rip = (unsigned)ri4.x | ((unsigned)ri4.y << 8) |
                             ((unsigned)ri4.z << 16) | ((unsigned)ri4.w << 24);

        float jacc = 0.f, kacc = 0.f;
        #pragma unroll
        for (int t = 0; t < 4; ++t) {
            const int ri = (int)((rip >> (8 * t)) & 0xFFu);
            const int ro = (int)((rpk >> (8 * t)) & 0xFFu);
            const float wt = wfl[t];
            if (ro > 0 && ro < ri) {                       // j-role
                const int w = t * 4 + (ro - 1);
                const unsigned N = cumtab[Pwv][w] +
                                   (unsigned)__popcll(cm[Pwv][w] & Pmask);
                jacc += wt * (float)N;
            }
            if (ro + 1 < ri) {                             // k-role
                const int wh = t * 4 + (ri - 1);
                const int wl = t * 4 + ro;
                const unsigned cLh = cumtab[Lwv][wh] +
                                     (unsigned)__popcll(cm[Lwv][wh] & Lmask);
                const unsigned cLl = cumtab[Lwv][wl] +
                                     (unsigned)__popcll(cm[Lwv][wl] & Lmask);
                const unsigned C = (cumtab[8][wh] - cLh) - (cumtab[8][wl] - cLl);
                kacc += wt * (float)C;
            }
        }
        contrib = jacc * thr - kacc * d;
    }

    #pragma unroll
    for (int off = 32; off > 0; off >>= 1)
        contrib += __shfl_down(contrib, off);
    if ((p & 63) == 0) red[wv] = contrib;
    __syncthreads();
    if (p == 0) {
        float s = 0.f;
        #pragma unroll
        for (int w = 0; w < 8; ++w) s += red[w];
        partial[bi] = s;
    }
}

// ---------------------------------------------------------------------------
// K3: reduce 384 partials -> out[0]
// ---------------------------------------------------------------------------
__global__ __launch_bounds__(256) void reduce_kernel(
    const float* __restrict__ partial, float* __restrict__ out)
{
    __shared__ float r[4];
    const int tid = threadIdx.x;
    float t = 0.f;
    for (int p = tid; p < NB; p += 256) t += partial[p];
    #pragma unroll
    for (int off = 32; off > 0; off >>= 1)
        t += __shfl_down(t, off);
    if ((tid & 63) == 0) r[tid >> 6] = t;
    __syncthreads();
    if (tid == 0) out[0] = r[0] + r[1] + r[2] + r[3];
}

extern "C" void kernel_launch(void* const* d_in, const int* in_sizes, int n_in,
                              void* d_out, int out_size, void* d_ws, size_t ws_size,
                              hipStream_t stream)
{
    (void)in_sizes; (void)n_in; (void)out_size; (void)ws_size;
    const float* emb  = (const float*)d_in[0];
    const float* tw   = (const float*)d_in[1];
    const int*   rank = (const int*)d_in[2];
    float* ws  = (float*)d_ws;
    float* out = (float*)d_out;

    prep_kernel<<<96, 256, 0, stream>>>(emb, tw, rank, ws);
    loss_kernel<<<NB, 512, 0, stream>>>(emb, ws + ET_OFF, rank,
                                        ws + WF_OFF, ws + PART_OFF);
    reduce_kernel<<<1, 256, 0, stream>>>(ws + PART_OFF, out);
}

// Round 10
// 23.422 us; speedup vs baseline: 1.1582x; 1.0329x over previous
//
#include <hip/hip_runtime.h>

#define NB   384
#define ND   256
#define EPSF 1e-6f
#define NBIN 512

// ws layout (floats):
#define WF_OFF   0                        // wf[4] = tw_t / count_t
#define PART_OFF 16                       // partial[384]
#define ETP_OFF  1024                     // uint2[64][384]: bf16-packed emb^T

__device__ __forceinline__ unsigned bf16rne(float f) {
    const unsigned b = __float_as_uint(f);
    return (b + 0x7FFFu + ((b >> 16) & 1u)) >> 16;   // round-nearest-even
}

// ---------------------------------------------------------------------------
// K1: transpose emb -> ETP[g][j] = bf16x4 of dims {4g..4g+3} of e_j.
// 32x32 LDS tile per block; block 0 also computes wf[t] = tw_t / count_t.
// ---------------------------------------------------------------------------
__global__ __launch_bounds__(256) void prep_kernel(
    const float* __restrict__ emb,
    const float* __restrict__ tw,
    const int*   __restrict__ rank,
    float* __restrict__ ws)
{
    __shared__ float    t[32][33];
    __shared__ unsigned hist[20];

    const int tid = threadIdx.x;
    const int dt  = blockIdx.x & 7;      // 8 d-tiles of 32
    const int jt  = blockIdx.x >> 3;     // 12 j-tiles of 32
    const int c   = tid & 31;
    const int r8  = tid >> 5;

    #pragma unroll
    for (int p = 0; p < 4; ++p) {
        const int j = jt * 32 + r8 + p * 8;
        const int d = dt * 32 + c;
        t[r8 + p * 8][c] = emb[(size_t)j * ND + d];    // coalesced
    }
    __syncthreads();

    // pack 4 consecutive dims of one j into uint2 (bf16 x4)
    const int jloc = tid & 31;
    const int gl   = tid >> 5;           // 0..7 (d-group within tile)
    const float v0 = t[jloc][gl * 4 + 0];
    const float v1 = t[jloc][gl * 4 + 1];
    const float v2 = t[jloc][gl * 4 + 2];
    const float v3 = t[jloc][gl * 4 + 3];
    uint2 o;
    o.x = bf16rne(v0) | (bf16rne(v1) << 16);
    o.y = bf16rne(v2) | (bf16rne(v3) << 16);
    uint2* etp = reinterpret_cast<uint2*>(ws + ETP_OFF);
    etp[(size_t)(dt * 8 + gl) * NB + jt * 32 + jloc] = o;   // coalesced 8B

    if (blockIdx.x == 0) {
        if (tid < 20) hist[tid] = 0u;
        __syncthreads();
        for (int e = tid; e < NB * 4; e += 256)
            atomicAdd(&hist[(e & 3) * 5 + rank[e]], 1u);
        __syncthreads();
        if (tid < 4) {
            double cnt = 0.0;
            unsigned below = 0;
            #pragma unroll
            for (int v = 0; v < 5; ++v) {
                unsigned hv = hist[tid * 5 + v];
                unsigned above = (unsigned)NB - below - hv;
                cnt += (double)hv * (double)below * (double)above;
                below += hv;
            }
            ws[WF_OFF + tid] = (cnt > 0.0) ? (float)((double)tw[tid] / cnt) : 0.f;
        }
    }
}

// ---------------------------------------------------------------------------
// K2 (fused, sort-free): one block per row i.
//  P1: d_p from bf16 ETP (8B coalesced lane loads); e_i via wave-uniform
//      global reads -> s_load (SMEM pipe) -- zero LDS traffic in the loop.
//  P2: row min/max -> integer bins-per-unit scale S (bin(d+1)==bin(d)+S)
//  P3: 512-bin histogram -> shfl prefix scan -> counting scatter of rank packs
//  P4: ballot cumulative-rank masks over d-grouped order
//  P5: j-role / k-role counting with bin-boundary cuts (pair sets identical
//      on both sides by construction)
// ---------------------------------------------------------------------------
__global__ __launch_bounds__(512) void loss_kernel(
    const float* __restrict__ emb,
    const uint2* __restrict__ etp,
    const int*   __restrict__ rank,
    const float* __restrict__ wf,
    float* __restrict__ partial)
{
    __shared__ unsigned hist[NBIN];
    __shared__ unsigned offs[NBIN + 1];
    __shared__ unsigned curs[NBIN];
    __shared__ unsigned srk[512];
    __shared__ unsigned long long cm[8][16];
    __shared__ unsigned cumtab[9][16];
    __shared__ unsigned wtot[8];
    __shared__ float    mmx[16];
    __shared__ float    sprm[2];
    __shared__ float    wfl[4];
    __shared__ float    red[8];

    const int p  = threadIdx.x;
    const int bi = blockIdx.x;
    const int wv = p >> 6;

    if (p < 4) wfl[p] = wf[p];
    hist[p] = 0u;
    if (p >= NB) srk[p] = 0xFFFFFFFFu;   // pads: rank bytes 0xFF (never counted)
    __syncthreads();

    // P1: distance (bf16 ej, f32 ei via scalar path)
    float d = 0.f;
    if (p < NB) {
        const float* ei = emb + (size_t)bi * ND;      // uniform -> s_load
        float acc = 0.f;
        for (int g0 = 0; g0 < 64; g0 += 8) {          // 8 batches of 8 loads
            uint2 l[8];
            #pragma unroll
            for (int u = 0; u < 8; ++u)
                l[u] = etp[(size_t)(g0 + u) * NB + p];
            #pragma unroll
            for (int u = 0; u < 8; ++u) {
                const int dd = (g0 + u) * 4;
                const float j0 = __uint_as_float(l[u].x << 16);
                const float j1 = __uint_as_float(l[u].x & 0xFFFF0000u);
                const float j2 = __uint_as_float(l[u].y << 16);
                const float j3 = __uint_as_float(l[u].y & 0xFFFF0000u);
                const float t0 = ei[dd + 0] - j0;
                const float t1 = ei[dd + 1] - j1;
                const float t2 = ei[dd + 2] - j2;
                const float t3 = ei[dd + 3] - j3;
                acc = fmaf(t0, t0, acc);
                acc = fmaf(t1, t1, acc);
                acc = fmaf(t2, t2, acc);
                acc = fmaf(t3, t3, acc);
            }
        }
        d = sqrtf(acc);
    }

    // P2: min/max -> integer scale
    float dl = (p < NB) ? d : 3.0e38f;
    float dh = (p < NB) ? d : -3.0e38f;
    #pragma unroll
    for (int off = 32; off > 0; off >>= 1) {
        dl = fminf(dl, __shfl_xor(dl, off, 64));
        dh = fmaxf(dh, __shfl_xor(dh, off, 64));
    }
    if ((p & 63) == 0) { mmx[wv] = dl; mmx[8 + wv] = dh; }
    __syncthreads();
    if (p == 0) {
        float mn = mmx[0], mx = mmx[8];
        #pragma unroll
        for (int w = 1; w < 8; ++w) {
            mn = fminf(mn, mmx[w]);
            mx = fmaxf(mx, mmx[8 + w]);
        }
        int S = (int)(511.0f / (mx - mn + 1.0f));
        if (S < 1) S = 1;
        sprm[0] = mn;
        sprm[1] = (float)S;
    }
    __syncthreads();
    const float dmin   = sprm[0];
    const float scaleF = sprm[1];
    const int   S      = (int)scaleF;

    // P3a: histogram
    int q = 0;
    unsigned rpk = 0xFFFFFFFFu;
    if (p < NB) {
        q = (int)((d - dmin) * scaleF);
        if (q > NBIN - 1) q = NBIN - 1;
        atomicAdd(&hist[q], 1u);
        const int4 r4 = *reinterpret_cast<const int4*>(rank + p * 4);
        rpk = (unsigned)r4.x | ((unsigned)r4.y << 8) |
              ((unsigned)r4.z << 16) | ((unsigned)r4.w << 24);
    }
    __syncthreads();

    // P3b: exclusive prefix over 512 bins
    const unsigned h = hist[p];
    unsigned inc = h;
    #pragma unroll
    for (int s = 1; s < 64; s <<= 1) {
        const unsigned o = __shfl_up(inc, s, 64);
        if ((p & 63) >= s) inc += o;
    }
    if ((p & 63) == 63) wtot[wv] = inc;
    __syncthreads();
    unsigned woff = 0;
    for (int w = 0; w < wv; ++w) woff += wtot[w];
    const unsigned excl = woff + inc - h;
    offs[p] = excl;
    curs[p] = excl;
    if (p == NBIN - 1) offs[NBIN] = excl + h;   // == NB
    __syncthreads();

    // P3c: counting scatter of rank packs into d-grouped order
    if (p < NB) {
        const unsigned pos = atomicAdd(&curs[q], 1u);
        srk[pos] = rpk;
    }
    __syncthreads();

    // P4: ballot cumulative-rank masks over scattered order
    const unsigned rsv = srk[p];
    #pragma unroll
    for (int t = 0; t < 4; ++t) {
        const unsigned rt = (rsv >> (8 * t)) & 0xFFu;
        #pragma unroll
        for (int w = 0; w < 4; ++w) {
            const unsigned long long m = __ballot(rt <= (unsigned)w);
            if ((p & 63) == 0) cm[wv][t * 4 + w] = m;
        }
    }
    __syncthreads();
    if (p < 16) {
        unsigned c = 0;
        #pragma unroll
        for (int w2 = 0; w2 < 8; ++w2) {
            cumtab[w2][p] = c;
            c += (unsigned)__popcll(cm[w2][p]);
        }
        cumtab[8][p] = c;
    }
    __syncthreads();

    // P5: per-element contribution (own exact d; cuts at bin boundaries)
    float contrib = 0.f;
    if (p < NB) {
        const float thr = d + 1.0f;
        const int jidx = (q + S > NBIN) ? NBIN : (q + S);
        const int kidx = (q - S + 1 < 0) ? 0 : (q - S + 1);
        const unsigned P = offs[jidx];     // j-role partners: pos <  P
        const unsigned L = offs[kidx];     // k-role partners: pos >= L
        const int Pwv = (int)(P >> 6), Lwv = (int)(L >> 6);
        const unsigned long long Pmask = (1ull << (P & 63)) - 1ull;
        const unsigned long long Lmask = (1ull << (L & 63)) - 1ull;

        const int4 ri4 = *reinterpret_cast<const int4*>(rank + bi * 4);
        const unsigned rip = (unsigned)ri4.x | ((unsigned)ri4.y << 8) |
                             ((unsigned)ri4.z << 16) | ((unsigned)ri4.w << 24);

        float jacc = 0.f, kacc = 0.f;
        #pragma unroll
        for (int t = 0; t < 4; ++t) {
            const int ri = (int)((rip >> (8 * t)) & 0xFFu);
            const int ro = (int)((rpk >> (8 * t)) & 0xFFu);
            const float wt = wfl[t];
            if (ro > 0 && ro < ri) {                       // j-role
                const int w = t * 4 + (ro - 1);
                const unsigned N = cumtab[Pwv][w] +
                                   (unsigned)__popcll(cm[Pwv][w] & Pmask);
                jacc += wt * (float)N;
            }
            if (ro + 1 < ri) {                             // k-role
                const int wh = t * 4 + (ri - 1);
                const int wl = t * 4 + ro;
                const unsigned cLh = cumtab[Lwv][wh] +
                                     (unsigned)__popcll(cm[Lwv][wh] & Lmask);
                const unsigned cLl = cumtab[Lwv][wl] +
                                     (unsigned)__popcll(cm[Lwv][wl] & Lmask);
                const unsigned C = (cumtab[8][wh] - cLh) - (cumtab[8][wl] - cLl);
                kacc += wt * (float)C;
            }
        }
        contrib = jacc * thr - kacc * d;
    }

    #pragma unroll
    for (int off = 32; off > 0; off >>= 1)
        contrib += __shfl_down(contrib, off);
    if ((p & 63) == 0) red[wv] = contrib;
    __syncthreads();
    if (p == 0) {
        float s = 0.f;
        #pragma unroll
        for (int w = 0; w < 8; ++w) s += red[w];
        partial[bi] = s;
    }
}

// ---------------------------------------------------------------------------
// K3: reduce 384 partials -> out[0]
// ---------------------------------------------------------------------------
__global__ __launch_bounds__(256) void reduce_kernel(
    const float* __restrict__ partial, float* __restrict__ out)
{
    __shared__ float r[4];
    const int tid = threadIdx.x;
    float t = 0.f;
    for (int p = tid; p < NB; p += 256) t += partial[p];
    #pragma unroll
    for (int off = 32; off > 0; off >>= 1)
        t += __shfl_down(t, off);
    if ((tid & 63) == 0) r[tid >> 6] = t;
    __syncthreads();
    if (tid == 0) out[0] = r[0] + r[1] + r[2] + r[3];
}

extern "C" void kernel_launch(void* const* d_in, const int* in_sizes, int n_in,
                              void* d_out, int out_size, void* d_ws, size_t ws_size,
                              hipStream_t stream)
{
    (void)in_sizes; (void)n_in; (void)out_size; (void)ws_size;
    const float* emb  = (const float*)d_in[0];
    const float* tw   = (const float*)d_in[1];
    const int*   rank = (const int*)d_in[2];
    float* ws  = (float*)d_ws;
    float* out = (float*)d_out;

    prep_kernel<<<96, 256, 0, stream>>>(emb, tw, rank, ws);
    loss_kernel<<<NB, 512, 0, stream>>>(
        emb, reinterpret_cast<const uint2*>(ws + ETP_OFF), rank,
        ws + WF_OFF, ws + PART_OFF);
    reduce_kernel<<<1, 256, 0, stream>>>(ws + PART_OFF, out);
}